// Round 18
// baseline (491.199 us; speedup 1.0000x reference)
//
#include <hip/hip_runtime.h>
#include <hip/hip_bf16.h>
#include <stdint.h>

#define DIN 4096
#define DOUT 4096
#define BK 64
#define NT (DIN / BK)   // 64 K-tiles

typedef __attribute__((ext_vector_type(8))) short short8;
typedef __attribute__((ext_vector_type(8))) unsigned short ushort8;
typedef __attribute__((ext_vector_type(4))) float f32x4;

__device__ inline unsigned short f2bf(float f) {
    union { float f; unsigned u; } v; v.f = f;
    unsigned r = v.u + 0x7fffu + ((v.u >> 16) & 1u);   // RNE
    return (unsigned short)(r >> 16);
}

// ---- prep 1: x (f32) -> bf16, 8 elems/thread (verified) ---------------------
__global__ void cvt_x_kernel(const float* __restrict__ x, ushort* __restrict__ xb, long n8) {
    long i = (long)blockIdx.x * blockDim.x + threadIdx.x;
    if (i >= n8) return;
    const float4* p = (const float4*)(x + i * 8);
    float4 v0 = p[0], v1 = p[1];
    ushort8 o;
    o[0] = f2bf(v0.x); o[1] = f2bf(v0.y); o[2] = f2bf(v0.z); o[3] = f2bf(v0.w);
    o[4] = f2bf(v1.x); o[5] = f2bf(v1.y); o[6] = f2bf(v1.z); o[7] = f2bf(v1.w);
    *(ushort8*)(xb + i * 8) = o;
}

// ---- prep 2: Wt[e][d] = bf16(base[d][e] + c*mask[d][e])  (verified) ---------
__global__ void make_wt_kernel(const float* __restrict__ base, const int* __restrict__ mask,
                               const float* __restrict__ coeff, ushort* __restrict__ wt) {
    __shared__ float tile[64][65];
    const float c = coeff[0];
    const int t = threadIdx.x;                 // 256 threads
    const int bd = blockIdx.x >> 6;
    const int be = blockIdx.x & 63;
    const int d0 = bd * 64, e0 = be * 64;
#pragma unroll
    for (int i = 0; i < 4; ++i) {
        int idx = i * 256 + t;
        int r = idx >> 4;
        int c4 = (idx & 15) << 2;
        const float4 bv = *(const float4*)(base + (size_t)(d0 + r) * DOUT + e0 + c4);
        const int4  mv = *(const int4*)(mask + (size_t)(d0 + r) * DOUT + e0 + c4);
        tile[r][c4 + 0] = bv.x + c * (float)mv.x;
        tile[r][c4 + 1] = bv.y + c * (float)mv.y;
        tile[r][c4 + 2] = bv.z + c * (float)mv.z;
        tile[r][c4 + 3] = bv.w + c * (float)mv.w;
    }
    __syncthreads();
#pragma unroll
    for (int i = 0; i < 8; ++i) {
        int idx = i * 256 + t;
        int r = idx >> 5;
        int p = (idx & 31) << 1;
        ushort2 o;
        o.x = f2bf(tile[p][r]);
        o.y = f2bf(tile[p + 1][r]);
        *(ushort2*)(wt + (size_t)(e0 + r) * DIN + d0 + p) = o;
    }
}

// ---- GEMM: 256x256, BK=64, r9 schedule at 16 waves (64x64 wave tiles) -------
// Round-18: occupancy attack. Same LDS layout/swizzle/stage economy as r9;
// 1024 threads -> 16 waves -> 4 waves/SIMD (was 2). Per-wave regs halve
// (acc 64 + frags 32 -> fits the 128-reg occupancy bucket). K-tile = 2 phases
// (kk0, kk1) x 16 MFMA.
// FIFO audit (per wave, 2 GLL per stage-pair, 1 GLL per STAGE_x):
//   steady entry: out = [kk1(U) 2, kk0(U+1) 2] = 4
//   ph1: +stage kk1(U+1) (2) -> 6; WAITV(4) drains kk1(U) [>=2 phases old];
//        BAR; MFMA(kk0)           <- all waves' WAITV precede BAR: kk1 safe
//   ph2: reads kk1; +stage kk0(U+2) (2) -> 6; BAR; MFMA(kk1)
//   boundary: WAITV(4) drains kk0(U+1) [staged ph2(U-1)]; BAR
// Overwrite safety (r9 argument): ph1's stage targets [buf^1][kk1], whose
// readers (ph2 of U-1) all passed the boundary BAR; ph2's stage targets
// [buf][kk0], whose readers issued their ds_reads before BAR(ph1).

#define MFMA(d, va, vb) d = __builtin_amdgcn_mfma_f32_16x16x32_bf16(va, vb, d, 0, 0, 0)

#define GLL(P, L) \
    __builtin_amdgcn_global_load_lds( \
        (const __attribute__((address_space(1))) void*)(P), \
        (__attribute__((address_space(3))) void*)(L), 16, 0, 0)

#define RDA(BUF,KK,MM) (*(const short8*)&lA[BUF][KK][aoff + (MM)*512])
#define RDB(BUF,KK,NN) (*(const short8*)&lB[BUF][KK][boff + (NN)*512])

#define STAGE_A(BUF,KK,OFE) GLL(gA0 + (OFE), &lA[BUF][KK][doff]);
#define STAGE_B(BUF,KK,OFE) GLL(gB0 + (OFE), &lB[BUF][KK][doff]);

#define WAITV(N)  asm volatile("s_waitcnt vmcnt(" #N ")" ::: "memory")
#define SBAR      __builtin_amdgcn_s_barrier()

#define MFMA16 \
    MFMA(acc[0][0],a0,b0); MFMA(acc[0][1],a0,b1); MFMA(acc[0][2],a0,b2); MFMA(acc[0][3],a0,b3); \
    MFMA(acc[1][0],a1,b0); MFMA(acc[1][1],a1,b1); MFMA(acc[1][2],a1,b2); MFMA(acc[1][3],a1,b3); \
    MFMA(acc[2][0],a2,b0); MFMA(acc[2][1],a2,b1); MFMA(acc[2][2],a2,b2); MFMA(acc[2][3],a2,b3); \
    MFMA(acc[3][0],a3,b0); MFMA(acc[3][1],a3,b1); MFMA(acc[3][2],a3,b2); MFMA(acc[3][3],a3,b3);

#define KTILE(BUF, G1, G2, NEXT, OFE1, OFE2) \
  { \
    short8 a0,a1,a2,a3,b0,b1,b2,b3; \
    /* ph1: kk0 */ \
    a0=RDA(BUF,0,0); a1=RDA(BUF,0,1); a2=RDA(BUF,0,2); a3=RDA(BUF,0,3); \
    b0=RDB(BUF,0,0); b1=RDB(BUF,0,1); b2=RDB(BUF,0,2); b3=RDB(BUF,0,3); \
    if (G1) { STAGE_A(1-(BUF), 1, OFE1) STAGE_B(1-(BUF), 1, OFE1) } \
    if (G1) { WAITV(4); } else { WAITV(0); } \
    SBAR; \
    __builtin_amdgcn_s_setprio(1); \
    MFMA16 \
    __builtin_amdgcn_s_setprio(0); \
    /* ph2: kk1 */ \
    a0=RDA(BUF,1,0); a1=RDA(BUF,1,1); a2=RDA(BUF,1,2); a3=RDA(BUF,1,3); \
    b0=RDB(BUF,1,0); b1=RDB(BUF,1,1); b2=RDB(BUF,1,2); b3=RDB(BUF,1,3); \
    if (G2) { STAGE_A(BUF, 0, OFE2) STAGE_B(BUF, 0, OFE2) } \
    SBAR; \
    __builtin_amdgcn_s_setprio(1); \
    MFMA16 \
    __builtin_amdgcn_s_setprio(0); \
    /* boundary */ \
    if (G2)        { WAITV(4); } \
    else if (NEXT) { WAITV(0); } \
    SBAR; \
    __builtin_amdgcn_sched_barrier(0); \
  }

__global__ __launch_bounds__(1024) void gemm_kernel(const ushort* __restrict__ A,
                                                    const ushort* __restrict__ Bt,
                                                    float* __restrict__ C) {
    __shared__ __align__(16) ushort lA[2][2][256 * 32];   // 64 KiB
    __shared__ __align__(16) ushort lB[2][2][256 * 32];   // 64 KiB

    const int tid = threadIdx.x;
    const int lane = tid & 63;
    const int wave = tid >> 6;                // 0..15

    const int nbn = DOUT / 256;               // 16
    const int nwg = gridDim.x;                // 512 (multiple of 8)
    int bid = blockIdx.x;
    int cpx = nwg >> 3;
    int s = (bid & 7) * cpx + (bid >> 3);     // XCD-contiguous chunks
    const int m0 = (s / nbn) * 256;
    const int n0 = (s % nbn) * 256;

    const int wr = wave >> 2;                 // 0..3  (M quarter, 64 rows)
    const int wc = wave & 3;                  // 0..3  (N quarter, 64 cols)
    const int fr = lane & 15;
    const int fq = lane >> 4;                 // 0..3

    // per-thread constant offsets (ushort elems); r9 swizzle: elem-xor ((fr>>1)&3)<<3
    const int sx = ((fr >> 1) & 3) << 3;
    const int aoff = (wr * 64 + fr) * 32 + ((fq << 3) ^ sx);
    const int boff = (wc * 64 + fr) * 32 + ((fq << 3) ^ sx);
    const int doff = tid * 8;                 // linear stage dest (1024*16B = 16KB region)
    const int st_r = tid >> 2;                // 0..255
    const int sce = ((tid & 3) << 3) ^ (((st_r >> 1) & 3) << 3);   // inv-swz source
    const ushort* gA0 = A  + (size_t)(m0 + st_r) * DIN + sce;
    const ushort* gB0 = Bt + (size_t)(n0 + st_r) * DIN + sce;

    f32x4 acc[4][4] = {};

    // prologue: kk0(0), kk1(0), kk0(1) staged (6 GLL/thread);
    // WAITV(4) drains kk0(0) -> entry state [kk1(0), kk0(1)] = steady
    STAGE_A(0, 0, 0)   STAGE_B(0, 0, 0)
    STAGE_A(0, 1, 32)  STAGE_B(0, 1, 32)
    STAGE_A(1, 0, 64)  STAGE_B(1, 0, 64)
    WAITV(4);
    SBAR;
    __builtin_amdgcn_sched_barrier(0);

    for (int u = 0; u < NT; u += 2) {
        KTILE(0, 1, (u + 2 < NT), 1, 96, 128)
        KTILE(1, (u + 2 < NT), (u + 3 < NT), (u + 2 < NT), 160, 192)
        gA0 += 128; gB0 += 128;
    }

    // epilogue: C/D frag layout col=fr, row=fq*4+j (verified)
#pragma unroll
    for (int a = 0; a < 4; ++a) {
        int grow = m0 + wr * 64 + a * 16 + fq * 4;
#pragma unroll
        for (int n = 0; n < 4; ++n) {
            int gcol = n0 + wc * 64 + n * 16 + fr;
#pragma unroll
            for (int j = 0; j < 4; ++j)
                C[(size_t)(grow + j) * DOUT + gcol] = acc[a][n][j];
        }
    }
}

extern "C" void kernel_launch(void* const* d_in, const int* in_sizes, int n_in,
                              void* d_out, int out_size, void* d_ws, size_t ws_size,
                              hipStream_t stream) {
    const float* x = (const float*)d_in[0];
    const float* base = (const float*)d_in[1];
    const float* coeff = (const float*)d_in[2];
    const int* mask = (const int*)d_in[3];
    float* out = (float*)d_out;

    const int M = in_sizes[0] / DIN;           // 8192
    ushort* xb = (ushort*)d_ws;                // M*DIN bf16  (64 MB)
    ushort* wt = xb + (size_t)M * DIN;         // DOUT*DIN bf16 (32 MB)

    long n8 = (long)M * DIN / 8;
    cvt_x_kernel<<<(int)((n8 + 255) / 256), 256, 0, stream>>>(x, xb, n8);
    make_wt_kernel<<<(DIN / 64) * (DOUT / 64), 256, 0, stream>>>(base, mask, coeff, wt);

    const int nwg = (M / 256) * (DOUT / 256);  // 512
    gemm_kernel<<<nwg, 1024, 0, stream>>>(xb, wt, out);
}

// Round 19
// 488.828 us; speedup vs baseline: 1.0048x; 1.0048x over previous
//
#include <hip/hip_runtime.h>
#include <hip/hip_bf16.h>
#include <stdint.h>

#define DIN 4096
#define DOUT 4096
#define BK 64
#define NT (DIN / BK)   // 64 K-tiles

typedef __attribute__((ext_vector_type(8))) short short8;
typedef __attribute__((ext_vector_type(8))) unsigned short ushort8;
typedef __attribute__((ext_vector_type(4))) float f32x4;

__device__ inline unsigned short f2bf(float f) {
    union { float f; unsigned u; } v; v.f = f;
    unsigned r = v.u + 0x7fffu + ((v.u >> 16) & 1u);   // RNE
    return (unsigned short)(r >> 16);
}

// ---- prep 1: x (f32) -> bf16, 8 elems/thread (verified) ---------------------
__global__ void cvt_x_kernel(const float* __restrict__ x, ushort* __restrict__ xb, long n8) {
    long i = (long)blockIdx.x * blockDim.x + threadIdx.x;
    if (i >= n8) return;
    const float4* p = (const float4*)(x + i * 8);
    float4 v0 = p[0], v1 = p[1];
    ushort8 o;
    o[0] = f2bf(v0.x); o[1] = f2bf(v0.y); o[2] = f2bf(v0.z); o[3] = f2bf(v0.w);
    o[4] = f2bf(v1.x); o[5] = f2bf(v1.y); o[6] = f2bf(v1.z); o[7] = f2bf(v1.w);
    *(ushort8*)(xb + i * 8) = o;
}

// ---- prep 2: Wt[e][d] = bf16(base[d][e] + c*mask[d][e])  (verified) ---------
__global__ void make_wt_kernel(const float* __restrict__ base, const int* __restrict__ mask,
                               const float* __restrict__ coeff, ushort* __restrict__ wt) {
    __shared__ float tile[64][65];
    const float c = coeff[0];
    const int t = threadIdx.x;                 // 256 threads
    const int bd = blockIdx.x >> 6;
    const int be = blockIdx.x & 63;
    const int d0 = bd * 64, e0 = be * 64;
#pragma unroll
    for (int i = 0; i < 4; ++i) {
        int idx = i * 256 + t;
        int r = idx >> 4;
        int c4 = (idx & 15) << 2;
        const float4 bv = *(const float4*)(base + (size_t)(d0 + r) * DOUT + e0 + c4);
        const int4  mv = *(const int4*)(mask + (size_t)(d0 + r) * DOUT + e0 + c4);
        tile[r][c4 + 0] = bv.x + c * (float)mv.x;
        tile[r][c4 + 1] = bv.y + c * (float)mv.y;
        tile[r][c4 + 2] = bv.z + c * (float)mv.z;
        tile[r][c4 + 3] = bv.w + c * (float)mv.w;
    }
    __syncthreads();
#pragma unroll
    for (int i = 0; i < 8; ++i) {
        int idx = i * 256 + t;
        int r = idx >> 5;
        int p = (idx & 31) << 1;
        ushort2 o;
        o.x = f2bf(tile[p][r]);
        o.y = f2bf(tile[p + 1][r]);
        *(ushort2*)(wt + (size_t)(e0 + r) * DIN + d0 + p) = o;
    }
}

// ---- GEMM: 256x256, BK=64, r9 schedule at 16 waves (64x64 wave tiles) -------
// Round-19: r18 with the spill fixed. __launch_bounds__(1024, 4) caps the
// allocator at 512/4 = 128 VGPRs -> the ~115 live regs (acc 64 + frags 32 +
// addr) fit spill-free, while keeping 4 waves/SIMD (2x r17's co-residency).
// r18's bare (1024) let the compiler target 8 waves/SIMD -> 64 VGPRs ->
// accumulator spills in the K-loop (WRITE_SIZE 131->262 MB, the r18 killer).
// Schedule/sync identical to r18 (passed, absmax-verified).

#define MFMA(d, va, vb) d = __builtin_amdgcn_mfma_f32_16x16x32_bf16(va, vb, d, 0, 0, 0)

#define GLL(P, L) \
    __builtin_amdgcn_global_load_lds( \
        (const __attribute__((address_space(1))) void*)(P), \
        (__attribute__((address_space(3))) void*)(L), 16, 0, 0)

#define RDA(BUF,KK,MM) (*(const short8*)&lA[BUF][KK][aoff + (MM)*512])
#define RDB(BUF,KK,NN) (*(const short8*)&lB[BUF][KK][boff + (NN)*512])

#define STAGE_A(BUF,KK,OFE) GLL(gA0 + (OFE), &lA[BUF][KK][doff]);
#define STAGE_B(BUF,KK,OFE) GLL(gB0 + (OFE), &lB[BUF][KK][doff]);

#define WAITV(N)  asm volatile("s_waitcnt vmcnt(" #N ")" ::: "memory")
#define SBAR      __builtin_amdgcn_s_barrier()

#define MFMA16 \
    MFMA(acc[0][0],a0,b0); MFMA(acc[0][1],a0,b1); MFMA(acc[0][2],a0,b2); MFMA(acc[0][3],a0,b3); \
    MFMA(acc[1][0],a1,b0); MFMA(acc[1][1],a1,b1); MFMA(acc[1][2],a1,b2); MFMA(acc[1][3],a1,b3); \
    MFMA(acc[2][0],a2,b0); MFMA(acc[2][1],a2,b1); MFMA(acc[2][2],a2,b2); MFMA(acc[2][3],a2,b3); \
    MFMA(acc[3][0],a3,b0); MFMA(acc[3][1],a3,b1); MFMA(acc[3][2],a3,b2); MFMA(acc[3][3],a3,b3);

#define KTILE(BUF, G1, G2, NEXT, OFE1, OFE2) \
  { \
    short8 a0,a1,a2,a3,b0,b1,b2,b3; \
    /* ph1: kk0 */ \
    a0=RDA(BUF,0,0); a1=RDA(BUF,0,1); a2=RDA(BUF,0,2); a3=RDA(BUF,0,3); \
    b0=RDB(BUF,0,0); b1=RDB(BUF,0,1); b2=RDB(BUF,0,2); b3=RDB(BUF,0,3); \
    if (G1) { STAGE_A(1-(BUF), 1, OFE1) STAGE_B(1-(BUF), 1, OFE1) } \
    if (G1) { WAITV(4); } else { WAITV(0); } \
    SBAR; \
    __builtin_amdgcn_s_setprio(1); \
    MFMA16 \
    __builtin_amdgcn_s_setprio(0); \
    /* ph2: kk1 */ \
    a0=RDA(BUF,1,0); a1=RDA(BUF,1,1); a2=RDA(BUF,1,2); a3=RDA(BUF,1,3); \
    b0=RDB(BUF,1,0); b1=RDB(BUF,1,1); b2=RDB(BUF,1,2); b3=RDB(BUF,1,3); \
    if (G2) { STAGE_A(BUF, 0, OFE2) STAGE_B(BUF, 0, OFE2) } \
    SBAR; \
    __builtin_amdgcn_s_setprio(1); \
    MFMA16 \
    __builtin_amdgcn_s_setprio(0); \
    /* boundary */ \
    if (G2)        { WAITV(4); } \
    else if (NEXT) { WAITV(0); } \
    SBAR; \
    __builtin_amdgcn_sched_barrier(0); \
  }

__global__ __launch_bounds__(1024, 4) void gemm_kernel(const ushort* __restrict__ A,
                                                       const ushort* __restrict__ Bt,
                                                       float* __restrict__ C) {
    __shared__ __align__(16) ushort lA[2][2][256 * 32];   // 64 KiB
    __shared__ __align__(16) ushort lB[2][2][256 * 32];   // 64 KiB

    const int tid = threadIdx.x;
    const int lane = tid & 63;
    const int wave = tid >> 6;                // 0..15

    const int nbn = DOUT / 256;               // 16
    const int nwg = gridDim.x;                // 512 (multiple of 8)
    int bid = blockIdx.x;
    int cpx = nwg >> 3;
    int s = (bid & 7) * cpx + (bid >> 3);     // XCD-contiguous chunks
    const int m0 = (s / nbn) * 256;
    const int n0 = (s % nbn) * 256;

    const int wr = wave >> 2;                 // 0..3  (M quarter, 64 rows)
    const int wc = wave & 3;                  // 0..3  (N quarter, 64 cols)
    const int fr = lane & 15;
    const int fq = lane >> 4;                 // 0..3

    // per-thread constant offsets (ushort elems); r9 swizzle: elem-xor ((fr>>1)&3)<<3
    const int sx = ((fr >> 1) & 3) << 3;
    const int aoff = (wr * 64 + fr) * 32 + ((fq << 3) ^ sx);
    const int boff = (wc * 64 + fr) * 32 + ((fq << 3) ^ sx);
    const int doff = tid * 8;                 // linear stage dest (16KB region)
    const int st_r = tid >> 2;                // 0..255
    const int sce = ((tid & 3) << 3) ^ (((st_r >> 1) & 3) << 3);   // inv-swz source
    const ushort* gA0 = A  + (size_t)(m0 + st_r) * DIN + sce;
    const ushort* gB0 = Bt + (size_t)(n0 + st_r) * DIN + sce;

    f32x4 acc[4][4] = {};

    // prologue: kk0(0), kk1(0), kk0(1) staged (6 GLL/thread);
    // WAITV(4) drains kk0(0) -> entry state [kk1(0), kk0(1)] = steady
    STAGE_A(0, 0, 0)   STAGE_B(0, 0, 0)
    STAGE_A(0, 1, 32)  STAGE_B(0, 1, 32)
    STAGE_A(1, 0, 64)  STAGE_B(1, 0, 64)
    WAITV(4);
    SBAR;
    __builtin_amdgcn_sched_barrier(0);

    for (int u = 0; u < NT; u += 2) {
        KTILE(0, 1, (u + 2 < NT), 1, 96, 128)
        KTILE(1, (u + 2 < NT), (u + 3 < NT), (u + 2 < NT), 160, 192)
        gA0 += 128; gB0 += 128;
    }

    // epilogue: C/D frag layout col=fr, row=fq*4+j (verified)
#pragma unroll
    for (int a = 0; a < 4; ++a) {
        int grow = m0 + wr * 64 + a * 16 + fq * 4;
#pragma unroll
        for (int n = 0; n < 4; ++n) {
            int gcol = n0 + wc * 64 + n * 16 + fr;
#pragma unroll
            for (int j = 0; j < 4; ++j)
                C[(size_t)(grow + j) * DOUT + gcol] = acc[a][n][j];
        }
    }
}

extern "C" void kernel_launch(void* const* d_in, const int* in_sizes, int n_in,
                              void* d_out, int out_size, void* d_ws, size_t ws_size,
                              hipStream_t stream) {
    const float* x = (const float*)d_in[0];
    const float* base = (const float*)d_in[1];
    const float* coeff = (const float*)d_in[2];
    const int* mask = (const int*)d_in[3];
    float* out = (float*)d_out;

    const int M = in_sizes[0] / DIN;           // 8192
    ushort* xb = (ushort*)d_ws;                // M*DIN bf16  (64 MB)
    ushort* wt = xb + (size_t)M * DIN;         // DOUT*DIN bf16 (32 MB)

    long n8 = (long)M * DIN / 8;
    cvt_x_kernel<<<(int)((n8 + 255) / 256), 256, 0, stream>>>(x, xb, n8);
    make_wt_kernel<<<(DIN / 64) * (DOUT / 64), 256, 0, stream>>>(base, mask, coeff, wt);

    const int nwg = (M / 256) * (DOUT / 256);  // 512
    gemm_kernel<<<nwg, 1024, 0, stream>>>(xb, wt, out);
}

// Round 20
// 435.061 us; speedup vs baseline: 1.1290x; 1.1236x over previous
//
#include <hip/hip_runtime.h>
#include <hip/hip_bf16.h>
#include <stdint.h>

#define DIN 4096
#define DOUT 4096
#define BK 64
#define NT (DIN / BK)   // 64 K-tiles

typedef __attribute__((ext_vector_type(8))) short short8;
typedef __attribute__((ext_vector_type(8))) unsigned short ushort8;
typedef __attribute__((ext_vector_type(4))) float f32x4;

__device__ inline unsigned short f2bf(float f) {
    union { float f; unsigned u; } v; v.f = f;
    unsigned r = v.u + 0x7fffu + ((v.u >> 16) & 1u);   // RNE
    return (unsigned short)(r >> 16);
}

// ---- prep 1: x (f32) -> bf16, 8 elems/thread (verified) ---------------------
__global__ void cvt_x_kernel(const float* __restrict__ x, ushort* __restrict__ xb, long n8) {
    long i = (long)blockIdx.x * blockDim.x + threadIdx.x;
    if (i >= n8) return;
    const float4* p = (const float4*)(x + i * 8);
    float4 v0 = p[0], v1 = p[1];
    ushort8 o;
    o[0] = f2bf(v0.x); o[1] = f2bf(v0.y); o[2] = f2bf(v0.z); o[3] = f2bf(v0.w);
    o[4] = f2bf(v1.x); o[5] = f2bf(v1.y); o[6] = f2bf(v1.z); o[7] = f2bf(v1.w);
    *(ushort8*)(xb + i * 8) = o;
}

// ---- prep 2: Wt[e][d] = bf16(base[d][e] + c*mask[d][e])  (verified) ---------
__global__ void make_wt_kernel(const float* __restrict__ base, const int* __restrict__ mask,
                               const float* __restrict__ coeff, ushort* __restrict__ wt) {
    __shared__ float tile[64][65];
    const float c = coeff[0];
    const int t = threadIdx.x;                 // 256 threads
    const int bd = blockIdx.x >> 6;
    const int be = blockIdx.x & 63;
    const int d0 = bd * 64, e0 = be * 64;
#pragma unroll
    for (int i = 0; i < 4; ++i) {
        int idx = i * 256 + t;
        int r = idx >> 4;
        int c4 = (idx & 15) << 2;
        const float4 bv = *(const float4*)(base + (size_t)(d0 + r) * DOUT + e0 + c4);
        const int4  mv = *(const int4*)(mask + (size_t)(d0 + r) * DOUT + e0 + c4);
        tile[r][c4 + 0] = bv.x + c * (float)mv.x;
        tile[r][c4 + 1] = bv.y + c * (float)mv.y;
        tile[r][c4 + 2] = bv.z + c * (float)mv.z;
        tile[r][c4 + 3] = bv.w + c * (float)mv.w;
    }
    __syncthreads();
#pragma unroll
    for (int i = 0; i < 8; ++i) {
        int idx = i * 256 + t;
        int r = idx >> 5;
        int p = (idx & 31) << 1;
        ushort2 o;
        o.x = f2bf(tile[p][r]);
        o.y = f2bf(tile[p + 1][r]);
        *(ushort2*)(wt + (size_t)(e0 + r) * DIN + d0 + p) = o;
    }
}

// ---- GEMM: 128x128 tile, BK=64, r18 protocol, 2 blocks/CU -------------------
// Round-20: occupancy test without the r18/r19 spill confound. 512 threads
// (r17's proven spill-free compilation regime), LDS halved to 64 KiB ->
// 2 blocks/CU -> 16 waves/CU = 4 waves/SIMD. Wave tile 32x64: acc[2][4]=32
// VGPR + frags 24 -> ~100 live, fits (512,4)'s 128-reg budget.
// Sync protocol = r18/r19 KTILE (passed twice), per-thread GLL counts
// identical: 1 GLL per STAGE, WAITV(4) mid-tile + boundary; audit carries.
// Cross-block overlap: while one block drains/barriers, the other block's
// waves occupy the MFMA pipe (m114) - no intra-block relaxation needed.

#define MFMA(d, va, vb) d = __builtin_amdgcn_mfma_f32_16x16x32_bf16(va, vb, d, 0, 0, 0)

#define GLL(P, L) \
    __builtin_amdgcn_global_load_lds( \
        (const __attribute__((address_space(1))) void*)(P), \
        (__attribute__((address_space(3))) void*)(L), 16, 0, 0)

#define RDA(BUF,KK,MM) (*(const short8*)&lA[BUF][KK][aoff + (MM)*512])
#define RDB(BUF,KK,NN) (*(const short8*)&lB[BUF][KK][boff + (NN)*512])

#define STAGE_A(BUF,KK,OFE) GLL(gA0 + (OFE), &lA[BUF][KK][doff]);
#define STAGE_B(BUF,KK,OFE) GLL(gB0 + (OFE), &lB[BUF][KK][doff]);

#define WAITV(N)  asm volatile("s_waitcnt vmcnt(" #N ")" ::: "memory")
#define SBAR      __builtin_amdgcn_s_barrier()

#define MFMA8 \
    MFMA(acc[0][0],a0,b0); MFMA(acc[0][1],a0,b1); MFMA(acc[0][2],a0,b2); MFMA(acc[0][3],a0,b3); \
    MFMA(acc[1][0],a1,b0); MFMA(acc[1][1],a1,b1); MFMA(acc[1][2],a1,b2); MFMA(acc[1][3],a1,b3);

#define KTILE(BUF, G1, G2, NEXT, OFE1, OFE2) \
  { \
    short8 a0,a1,b0,b1,b2,b3; \
    /* ph1: kk0 */ \
    a0=RDA(BUF,0,0); a1=RDA(BUF,0,1); \
    b0=RDB(BUF,0,0); b1=RDB(BUF,0,1); b2=RDB(BUF,0,2); b3=RDB(BUF,0,3); \
    if (G1) { STAGE_A(1-(BUF), 1, OFE1) STAGE_B(1-(BUF), 1, OFE1) } \
    if (G1) { WAITV(4); } else { WAITV(0); } \
    SBAR; \
    __builtin_amdgcn_s_setprio(1); \
    MFMA8 \
    __builtin_amdgcn_s_setprio(0); \
    /* ph2: kk1 */ \
    a0=RDA(BUF,1,0); a1=RDA(BUF,1,1); \
    b0=RDB(BUF,1,0); b1=RDB(BUF,1,1); b2=RDB(BUF,1,2); b3=RDB(BUF,1,3); \
    if (G2) { STAGE_A(BUF, 0, OFE2) STAGE_B(BUF, 0, OFE2) } \
    SBAR; \
    __builtin_amdgcn_s_setprio(1); \
    MFMA8 \
    __builtin_amdgcn_s_setprio(0); \
    /* boundary */ \
    if (G2)        { WAITV(4); } \
    else if (NEXT) { WAITV(0); } \
    SBAR; \
    __builtin_amdgcn_sched_barrier(0); \
  }

__global__ __launch_bounds__(512, 4) void gemm_kernel(const ushort* __restrict__ A,
                                                      const ushort* __restrict__ Bt,
                                                      float* __restrict__ C) {
    __shared__ __align__(16) ushort lA[2][2][128 * 32];   // 32 KiB
    __shared__ __align__(16) ushort lB[2][2][128 * 32];   // 32 KiB

    const int tid = threadIdx.x;
    const int lane = tid & 63;
    const int wave = tid >> 6;                // 0..7

    const int nbn = DOUT / 128;               // 32
    const int nwg = gridDim.x;                // 2048 (multiple of 8)
    int bid = blockIdx.x;
    int cpx = nwg >> 3;
    int s = (bid & 7) * cpx + (bid >> 3);     // XCD-contiguous chunks
    const int m0 = (s / nbn) * 128;
    const int n0 = (s % nbn) * 128;

    const int wr = wave >> 1;                 // 0..3  (M quarter, 32 rows)
    const int wc = wave & 1;                  // 0..1  (N half, 64 cols)
    const int fr = lane & 15;
    const int fq = lane >> 4;                 // 0..3

    // per-thread constant offsets (ushort elems); r9 swizzle: elem-xor ((fr>>1)&3)<<3
    const int sx = ((fr >> 1) & 3) << 3;
    const int aoff = (wr * 32 + fr) * 32 + ((fq << 3) ^ sx);
    const int boff = (wc * 64 + fr) * 32 + ((fq << 3) ^ sx);
    const int doff = tid * 8;                 // linear stage dest (8KB region)
    const int st_r = tid >> 2;                // 0..127
    const int sce = ((tid & 3) << 3) ^ (((st_r >> 1) & 3) << 3);   // inv-swz source
    const ushort* gA0 = A  + (size_t)(m0 + st_r) * DIN + sce;
    const ushort* gB0 = Bt + (size_t)(n0 + st_r) * DIN + sce;

    f32x4 acc[2][4] = {};

    // prologue: kk0(0), kk1(0), kk0(1) staged (6 GLL/thread);
    // WAITV(4) drains kk0(0) -> entry state [kk1(0), kk0(1)] = steady
    STAGE_A(0, 0, 0)   STAGE_B(0, 0, 0)
    STAGE_A(0, 1, 32)  STAGE_B(0, 1, 32)
    STAGE_A(1, 0, 64)  STAGE_B(1, 0, 64)
    WAITV(4);
    SBAR;
    __builtin_amdgcn_sched_barrier(0);

    for (int u = 0; u < NT; u += 2) {
        KTILE(0, 1, (u + 2 < NT), 1, 96, 128)
        KTILE(1, (u + 2 < NT), (u + 3 < NT), (u + 2 < NT), 160, 192)
        gA0 += 128; gB0 += 128;
    }

    // epilogue: C/D frag layout col=fr, row=fq*4+j (verified)
#pragma unroll
    for (int a = 0; a < 2; ++a) {
        int grow = m0 + wr * 32 + a * 16 + fq * 4;
#pragma unroll
        for (int n = 0; n < 4; ++n) {
            int gcol = n0 + wc * 64 + n * 16 + fr;
#pragma unroll
            for (int j = 0; j < 4; ++j)
                C[(size_t)(grow + j) * DOUT + gcol] = acc[a][n][j];
        }
    }
}

extern "C" void kernel_launch(void* const* d_in, const int* in_sizes, int n_in,
                              void* d_out, int out_size, void* d_ws, size_t ws_size,
                              hipStream_t stream) {
    const float* x = (const float*)d_in[0];
    const float* base = (const float*)d_in[1];
    const float* coeff = (const float*)d_in[2];
    const int* mask = (const int*)d_in[3];
    float* out = (float*)d_out;

    const int M = in_sizes[0] / DIN;           // 8192
    ushort* xb = (ushort*)d_ws;                // M*DIN bf16  (64 MB)
    ushort* wt = xb + (size_t)M * DIN;         // DOUT*DIN bf16 (32 MB)

    long n8 = (long)M * DIN / 8;
    cvt_x_kernel<<<(int)((n8 + 255) / 256), 256, 0, stream>>>(x, xb, n8);
    make_wt_kernel<<<(DIN / 64) * (DOUT / 64), 256, 0, stream>>>(base, mask, coeff, wt);

    const int nwg = (M / 128) * (DOUT / 128);  // 2048
    gemm_kernel<<<nwg, 512, 0, stream>>>(xb, wt, out);
}

// Round 21
// 316.232 us; speedup vs baseline: 1.5533x; 1.3758x over previous
//
#include <hip/hip_runtime.h>
#include <hip/hip_bf16.h>
#include <stdint.h>

#define DIN 4096
#define DOUT 4096
#define BK 64
#define NT (DIN / BK)   // 64 K-tiles

typedef __attribute__((ext_vector_type(8))) short short8;
typedef __attribute__((ext_vector_type(8))) unsigned short ushort8;
typedef __attribute__((ext_vector_type(4))) float f32x4;

__device__ inline unsigned short f2bf(float f) {
    union { float f; unsigned u; } v; v.f = f;
    unsigned r = v.u + 0x7fffu + ((v.u >> 16) & 1u);   // RNE
    return (unsigned short)(r >> 16);
}

// ---- prep 1: x (f32) -> bf16, 8 elems/thread --------------------------------
__global__ void cvt_x_kernel(const float* __restrict__ x, ushort* __restrict__ xb, long n8) {
    long i = (long)blockIdx.x * blockDim.x + threadIdx.x;
    if (i >= n8) return;
    const float4* p = (const float4*)(x + i * 8);
    float4 v0 = p[0], v1 = p[1];
    ushort8 o;
    o[0] = f2bf(v0.x); o[1] = f2bf(v0.y); o[2] = f2bf(v0.z); o[3] = f2bf(v0.w);
    o[4] = f2bf(v1.x); o[5] = f2bf(v1.y); o[6] = f2bf(v1.z); o[7] = f2bf(v1.w);
    *(ushort8*)(xb + i * 8) = o;
}

// ---- prep 2: Wt[e][d] = bf16(base[d][e] + c*mask[d][e])  (64x64 LDS transpose)
__global__ void make_wt_kernel(const float* __restrict__ base, const int* __restrict__ mask,
                               const float* __restrict__ coeff, ushort* __restrict__ wt) {
    __shared__ float tile[64][65];
    const float c = coeff[0];
    const int t = threadIdx.x;                 // 256 threads
    const int bd = blockIdx.x >> 6;            // d-tile
    const int be = blockIdx.x & 63;            // e-tile
    const int d0 = bd * 64, e0 = be * 64;
#pragma unroll
    for (int i = 0; i < 4; ++i) {
        int idx = i * 256 + t;                 // 0..1023 float4-index
        int r = idx >> 4;                      // d-row 0..63
        int c4 = (idx & 15) << 2;              // e-col
        const float4 bv = *(const float4*)(base + (size_t)(d0 + r) * DOUT + e0 + c4);
        const int4  mv = *(const int4*)(mask + (size_t)(d0 + r) * DOUT + e0 + c4);
        tile[r][c4 + 0] = bv.x + c * (float)mv.x;
        tile[r][c4 + 1] = bv.y + c * (float)mv.y;
        tile[r][c4 + 2] = bv.z + c * (float)mv.z;
        tile[r][c4 + 3] = bv.w + c * (float)mv.w;
    }
    __syncthreads();
#pragma unroll
    for (int i = 0; i < 8; ++i) {
        int idx = i * 256 + t;                 // 0..2047 pair index
        int r = idx >> 5;                      // e-row 0..63
        int p = (idx & 31) << 1;               // d-col pair
        ushort2 o;
        o.x = f2bf(tile[p][r]);
        o.y = f2bf(tile[p + 1][r]);
        *(ushort2*)(wt + (size_t)(e0 + r) * DIN + d0 + p) = o;
    }
}

// ---- GEMM: 256x256 tile, BK=64, 8-phase, de-lockstepped (r9/r17 best) -------
// Session optimum: 272us GEMM (~1010 TF, 40% dense peak), MfmaUtil ~46%,
// 0 bank conflicts, no spills. Post-MFMA barriers removed (5 barriers per
// K-tile); every STAGE issue protected by a PRE-MFMA barrier; vmcnt protocol:
// mid-tile WAITV(6) before ph2 reads, boundary WAITV(6)/WAITV(0) - all waits
// target loads >=3 phases old. Waves de-phase by one region (setprio 1/0
// gives the MFMA wave priority while its sibling issues reads/stages).

#define MFMA(d, va, vb) d = __builtin_amdgcn_mfma_f32_16x16x32_bf16(va, vb, d, 0, 0, 0)

#define GLL(P, L) \
    __builtin_amdgcn_global_load_lds( \
        (const __attribute__((address_space(1))) void*)(P), \
        (__attribute__((address_space(3))) void*)(L), 16, 0, 0)

#define RDA(BUF,KK,OH,MM) (*(const short8*)&lA[BUF][KK][aoff + (OH)*2048 + (MM)*512])
#define RDB(BUF,KK,NN)    (*(const short8*)&lB[BUF][KK][boff + (NN)*512])

#define STAGE_A(BUF,KK,OFE) { GLL(gA0 + (OFE), &lA[BUF][KK][doff]); \
                              GLL(gA1 + (OFE), &lA[BUF][KK][doff + 4096]); }
#define STAGE_B(BUF,KK,OFE) { GLL(gB0 + (OFE), &lB[BUF][KK][doff]); \
                              GLL(gB1 + (OFE), &lB[BUF][KK][doff + 4096]); }

#define WAITV(N)  asm volatile("s_waitcnt vmcnt(" #N ")" ::: "memory")

#define PHASE_CORE(AOFF) \
    __builtin_amdgcn_s_barrier(); \
    __builtin_amdgcn_s_setprio(1); \
    MFMA(acc[AOFF+0][0],a0,b0); MFMA(acc[AOFF+0][1],a0,b1); MFMA(acc[AOFF+0][2],a0,b2); MFMA(acc[AOFF+0][3],a0,b3); \
    MFMA(acc[AOFF+1][0],a1,b0); MFMA(acc[AOFF+1][1],a1,b1); MFMA(acc[AOFF+1][2],a1,b2); MFMA(acc[AOFF+1][3],a1,b3); \
    MFMA(acc[AOFF+2][0],a2,b0); MFMA(acc[AOFF+2][1],a2,b1); MFMA(acc[AOFF+2][2],a2,b2); MFMA(acc[AOFF+2][3],a2,b3); \
    MFMA(acc[AOFF+3][0],a3,b0); MFMA(acc[AOFF+3][1],a3,b1); MFMA(acc[AOFF+3][2],a3,b2); MFMA(acc[AOFF+3][3],a3,b3); \
    __builtin_amdgcn_s_setprio(0);

// K-tile: 4 phases; stage schedule:
//  ph1: stage A.kk1(U+1)->other buf   ph2: stage B.kk1(U+1)
//  ph3: stage A.kk0(U+2)->this buf    ph4: stage B.kk0(U+2)
#define KTILE(BUF, G1, G2, NEXT, OFE1, OFE2) \
  { \
    short8 a0,a1,a2,a3,b0,b1,b2,b3; \
    a0=RDA(BUF,0,0,0); a1=RDA(BUF,0,0,1); a2=RDA(BUF,0,0,2); a3=RDA(BUF,0,0,3); \
    b0=RDB(BUF,0,0); b1=RDB(BUF,0,1); b2=RDB(BUF,0,2); b3=RDB(BUF,0,3); \
    if (G1) STAGE_A(1-(BUF), 1, OFE1) \
    PHASE_CORE(0) \
    WAITV(6); \
    a0=RDA(BUF,0,1,0); a1=RDA(BUF,0,1,1); a2=RDA(BUF,0,1,2); a3=RDA(BUF,0,1,3); \
    if (G1) STAGE_B(1-(BUF), 1, OFE1) \
    PHASE_CORE(4) \
    a0=RDA(BUF,1,0,0); a1=RDA(BUF,1,0,1); a2=RDA(BUF,1,0,2); a3=RDA(BUF,1,0,3); \
    b0=RDB(BUF,1,0); b1=RDB(BUF,1,1); b2=RDB(BUF,1,2); b3=RDB(BUF,1,3); \
    if (G2) STAGE_A(BUF, 0, OFE2) \
    PHASE_CORE(0) \
    a0=RDA(BUF,1,1,0); a1=RDA(BUF,1,1,1); a2=RDA(BUF,1,1,2); a3=RDA(BUF,1,1,3); \
    if (G2) STAGE_B(BUF, 0, OFE2) \
    PHASE_CORE(4) \
    if (G2)        { WAITV(6); } \
    else if (NEXT) { WAITV(0); } \
    __builtin_amdgcn_s_barrier(); \
    __builtin_amdgcn_sched_barrier(0); \
  }

__global__ __launch_bounds__(512, 2) void gemm_kernel(const ushort* __restrict__ A,
                                                      const ushort* __restrict__ Bt,
                                                      float* __restrict__ C) {
    __shared__ __align__(16) ushort lA[2][2][256 * 32];
    __shared__ __align__(16) ushort lB[2][2][256 * 32];

    const int tid = threadIdx.x;
    const int lane = tid & 63;
    const int wave = tid >> 6;

    const int nbn = DOUT / 256;               // 16
    const int nwg = gridDim.x;                // 512 (multiple of 8)
    int bid = blockIdx.x;
    int cpx = nwg >> 3;
    int s = (bid & 7) * cpx + (bid >> 3);     // XCD-contiguous chunks
    const int m0 = (s / nbn) * 256;
    const int n0 = (s % nbn) * 256;

    const int wr = wave >> 2;                 // 0..1  (M half)
    const int wc = wave & 3;                  // 0..3  (N quarter)
    const int fr = lane & 15;
    const int fq = lane >> 4;                 // 0..3

    const int st_r = tid >> 2;                // 0..127

    // per-thread constant offsets (ushort elems); read swizzle elem-xor ((fr>>1)&3)<<3
    const int sx = ((fr >> 1) & 3) << 3;
    const int aoff = (wr * 128 + fr) * 32 + ((fq << 3) ^ sx);
    const int boff = (wc * 64 + fr) * 32 + ((fq << 3) ^ sx);
    const int doff = tid * 8;                 // linear stage dest
    const int sce = ((tid & 3) << 3) ^ (((st_r >> 1) & 3) << 3);   // inv-swz source
    const ushort* gA0 = A  + (size_t)(m0 + st_r) * DIN + sce;
    const ushort* gA1 = gA0 + (size_t)128 * DIN;
    const ushort* gB0 = Bt + (size_t)(n0 + st_r) * DIN + sce;
    const ushort* gB1 = gB0 + (size_t)128 * DIN;

    f32x4 acc[8][4] = {};

    // prologue: tile0 both halves + tile1.kk0 staged (12 GLL/wave)
    STAGE_A(0, 0, 0)   STAGE_B(0, 0, 0)
    STAGE_A(0, 1, 32)  STAGE_B(0, 1, 32)
    STAGE_A(1, 0, 64)  STAGE_B(1, 0, 64)
    WAITV(6);
    __builtin_amdgcn_s_barrier();
    __builtin_amdgcn_sched_barrier(0);

    for (int u = 0; u < NT; u += 2) {
        KTILE(0, 1, (u + 2 < NT), 1, 96, 128)
        KTILE(1, (u + 2 < NT), (u + 3 < NT), (u + 2 < NT), 160, 192)
        gA0 += 128; gA1 += 128; gB0 += 128; gB1 += 128;
    }

    // epilogue: C/D frag layout col=fr, row=fq*4+j
#pragma unroll
    for (int a = 0; a < 8; ++a) {
        int grow = m0 + wr * 128 + (a >> 2) * 64 + (a & 3) * 16 + fq * 4;
#pragma unroll
        for (int n = 0; n < 4; ++n) {
            int gcol = n0 + wc * 64 + n * 16 + fr;
#pragma unroll
            for (int j = 0; j < 4; ++j)
                C[(size_t)(grow + j) * DOUT + gcol] = acc[a][n][j];
        }
    }
}

extern "C" void kernel_launch(void* const* d_in, const int* in_sizes, int n_in,
                              void* d_out, int out_size, void* d_ws, size_t ws_size,
                              hipStream_t stream) {
    const float* x = (const float*)d_in[0];
    const float* base = (const float*)d_in[1];
    const float* coeff = (const float*)d_in[2];
    const int* mask = (const int*)d_in[3];
    float* out = (float*)d_out;

    const int M = in_sizes[0] / DIN;           // 8192
    ushort* xb = (ushort*)d_ws;                // M*DIN bf16  (64 MB)
    ushort* wt = xb + (size_t)M * DIN;         // DOUT*DIN bf16 (32 MB)

    long n8 = (long)M * DIN / 8;
    cvt_x_kernel<<<(int)((n8 + 255) / 256), 256, 0, stream>>>(x, xb, n8);
    make_wt_kernel<<<(DIN / 64) * (DOUT / 64), 256, 0, stream>>>(base, mask, coeff, wt);

    const int nwg = (M / 256) * (DOUT / 256);  // 512
    gemm_kernel<<<nwg, 512, 0, stream>>>(xb, wt, out);
}